// Round 1
// 115.631 us; speedup vs baseline: 1.0585x; 1.0585x over previous
//
#include <hip/hip_runtime.h>
#include <hip/hip_fp16.h>

#define B_N 1024
#define D_K 128
#define C_N 100000
#define CCHUNK 80            // 1250 * 80 == 100000 exactly, multiple of 16
#define NCC 1250
#define BSPLIT 2             // each main block handles 512 b's
#define NBLK_MAIN (NCC * BSPLIT)
#define NREP 8               // negsum replicas to cut atomic contention
#define EPSN 1e-12f
#define XSCL 2.8853900817779268f   // 2*log2(e): main computes exp2(acc) = exp(2*x.p_hat)

typedef _Float16 half8 __attribute__((ext_vector_type(8)));
typedef float floatx4 __attribute__((ext_vector_type(4)));

union U16 { uint4 u; half8 h; };

#if __has_builtin(__builtin_amdgcn_exp2f)
__device__ __forceinline__ float exp2_hw(float x) { return __builtin_amdgcn_exp2f(x); }
#else
__device__ __forceinline__ float exp2_hw(float x) {
    float r; asm("v_exp_f32 %0, %1" : "=v"(r) : "v"(x)); return r;
}
#endif

__device__ __forceinline__ unsigned int pack2h(float a, float b) {
    union { _Float16 h[2]; unsigned int u; } p;
    p.h[0] = (_Float16)a; p.h[1] = (_Float16)b;
    return p.u;
}

// ---------------------------------------------------------------------------
// Prep: per-row ||x||^2, w[b]=exp(-||x||^2-1), xs -> fp16 fragment-order
// scaled by 2*log2(e) so main's acc = log2(e)*2*x.p_hat feeds v_exp_f32
// directly. Exact fp32 positive distance posd[b], zero negsum replicas.
// One wave per row b.
// ---------------------------------------------------------------------------
__global__ __launch_bounds__(256) void prep_kernel(
    const float* __restrict__ xs, const int* __restrict__ ys,
    const float* __restrict__ proxies,
    unsigned int* __restrict__ xfrag, float* __restrict__ w,
    float* __restrict__ posd, float* __restrict__ negsumR)
{
    int tid  = threadIdx.x;
    int gid  = blockIdx.x * 256 + tid;
    if (gid < B_N * NREP) negsumR[gid] = 0.0f;

    int wave = tid >> 6, lane = tid & 63;
    int b = blockIdx.x * 4 + wave;   // grid = 256 blocks -> b in [0,1024)

    const float2 xv = ((const float2*)(xs + (size_t)b * D_K))[lane];
    float ss = xv.x * xv.x + xv.y * xv.y;
    #pragma unroll
    for (int m = 1; m < 64; m <<= 1) ss += __shfl_xor(ss, m, 64);
    float xsq = ss;

    // fragment-order write of XSCL*x: element (b, k=2*lane, 2*lane+1)
    {
        int f  = lane >> 4;
        int m4 = (lane >> 2) & 3;
        int j  = lane & 3;
        int idx = ((((b >> 4) * 4 + f) * 64) + ((b & 15) | (m4 << 4))) * 4 + j;
        xfrag[idx] = pack2h(XSCL * xv.x, XSCL * xv.y);
    }

    // positive proxy: exact fp32 dot + norm
    int y = ys[b];
    const float2 pv = ((const float2*)(proxies + (size_t)y * D_K))[lane];
    float dt = xv.x * pv.x + xv.y * pv.y;
    float pp = pv.x * pv.x + pv.y * pv.y;
    #pragma unroll
    for (int m = 1; m < 64; m <<= 1) {
        dt += __shfl_xor(dt, m, 64);
        pp += __shfl_xor(pp, m, 64);
    }
    if (lane == 0) {
        w[b] = __expf(-xsq - 1.0f);
        float nrm = fmaxf(sqrtf(pp), EPSN);
        posd[b] = xsq + 1.0f - 2.0f * (dt / nrm);
    }
}

// ---------------------------------------------------------------------------
// Stage helper: reduce ||p||^2 over the 8 lanes of a row, normalize,
// convert to fp16 and write both uint4 fragments into LDS (A-frag order).
// ---------------------------------------------------------------------------
__device__ __forceinline__ void stage_row(
    uint4* __restrict__ ldsP,
    float4 v0, float4 v1, float4 v2, float4 v3, int r, int L)
{
    float ss = v0.x*v0.x + v0.y*v0.y + v0.z*v0.z + v0.w*v0.w
             + v1.x*v1.x + v1.y*v1.y + v1.z*v1.z + v1.w*v1.w
             + v2.x*v2.x + v2.y*v2.y + v2.z*v2.z + v2.w*v2.w
             + v3.x*v3.x + v3.y*v3.y + v3.z*v3.z + v3.w*v3.w;
    ss += __shfl_xor(ss, 1, 64);
    ss += __shfl_xor(ss, 2, 64);
    ss += __shfl_xor(ss, 4, 64);
    float sc = 1.0f / fmaxf(sqrtf(ss), EPSN);

    union { _Float16 h[8]; uint4 u; } pa, pb;
    pa.h[0]=(_Float16)(v0.x*sc); pa.h[1]=(_Float16)(v0.y*sc);
    pa.h[2]=(_Float16)(v0.z*sc); pa.h[3]=(_Float16)(v0.w*sc);
    pa.h[4]=(_Float16)(v1.x*sc); pa.h[5]=(_Float16)(v1.y*sc);
    pa.h[6]=(_Float16)(v1.z*sc); pa.h[7]=(_Float16)(v1.w*sc);
    pb.h[0]=(_Float16)(v2.x*sc); pb.h[1]=(_Float16)(v2.y*sc);
    pb.h[2]=(_Float16)(v2.z*sc); pb.h[3]=(_Float16)(v2.w*sc);
    pb.h[4]=(_Float16)(v3.x*sc); pb.h[5]=(_Float16)(v3.y*sc);
    pb.h[6]=(_Float16)(v3.z*sc); pb.h[7]=(_Float16)(v3.w*sc);

    int cb = r >> 4, rc = r & 15;
    int f  = L >> 1;
    int mA = (L * 2) & 3;
    int mB = (L * 2 + 1) & 3;
    ldsP[(cb * 4 + f) * 64 + (rc | (mA << 4))] = pa.u;
    ldsP[(cb * 4 + f) * 64 + (rc | (mB << 4))] = pb.u;
}

// ---------------------------------------------------------------------------
// Main: block = (c-chunk of 80, b-half of 512). Stage+normalize 80 proxy
// rows into LDS (A-frag order), wave w owns 128 b's (4 b-groups of 32 to
// keep the X-fragment register cache at 32 VGPRs -> higher occupancy).
// acc = log2e*2*x.p_hat via mfma_f32_16x16x32_f16; accumulate
// sum_c exp2(acc) per b, atomicAdd into striped negsum replica (w folded
// into final_kernel).
// ---------------------------------------------------------------------------
__global__ __launch_bounds__(256, 4) void main_kernel(
    const float* __restrict__ proxies,
    const uint4* __restrict__ xfrag,
    float* __restrict__ negsumR)
{
    __shared__ uint4 ldsP[CCHUNK * 8];   // 80 rows * 128 k * 2B = 10 KB

    int tid = threadIdx.x;
    int bx  = blockIdx.x;
    int cc  = bx >> 1;          // c-chunk id (adjacent blocks share -> L2 hit)
    int bs  = bx & 1;           // b-half id
    int c0  = cc * CCHUNK;

    // ---- stage + normalize: 8 lanes per row, all loads issued up front ----
    {
        int L  = tid & 7;        // lane within row: covers k = L*16 .. L*16+15
        int rb = tid >> 3;       // 0..31
        const float* base = proxies + (size_t)c0 * D_K + L * 16;
        const float4* s0 = (const float4*)(base + (size_t)rb * D_K);
        const float4* s1 = (const float4*)(base + (size_t)(rb + 32) * D_K);
        float4 A0 = s0[0], A1 = s0[1], A2 = s0[2], A3 = s0[3];
        float4 B0 = s1[0], B1 = s1[1], B2 = s1[2], B3 = s1[3];
        float4 C0, C1, C2, C3;
        if (rb < 16) {
            const float4* s2 = (const float4*)(base + (size_t)(rb + 64) * D_K);
            C0 = s2[0]; C1 = s2[1]; C2 = s2[2]; C3 = s2[3];
        }
        stage_row(ldsP, A0, A1, A2, A3, rb,      L);
        stage_row(ldsP, B0, B1, B2, B3, rb + 32, L);
        if (rb < 16)
            stage_row(ldsP, C0, C1, C2, C3, rb + 64, L);
    }
    __syncthreads();

    // ---- compute ----
    int wave  = tid >> 6, lane = tid & 63;
    int b0    = bs * 512 + wave * 128;       // this wave's 128 b's
    int t0    = b0 >> 4;                     // first 16-b tile index
    float* nsr = negsumR + (size_t)(bx & (NREP - 1)) * B_N;

    #pragma unroll 1
    for (int bg = 0; bg < 4; ++bg) {
        // register-cache X fragments for 2 b-tiles (32 b's, 32 VGPRs)
        uint4 xf[2][4];
        #pragma unroll
        for (int bt = 0; bt < 2; ++bt)
            #pragma unroll
            for (int f = 0; f < 4; ++f)
                xf[bt][f] = xfrag[((t0 + bg * 2 + bt) * 4 + f) * 64 + lane];

        float sv[2] = {0.f, 0.f};

        #pragma unroll 1
        for (int cb = 0; cb < CCHUNK / 16; ++cb) {
            uint4 a[4];
            #pragma unroll
            for (int f = 0; f < 4; ++f)
                a[f] = ldsP[(cb * 4 + f) * 64 + lane];

            #pragma unroll
            for (int bt = 0; bt < 2; ++bt) {
                floatx4 acc = {0.f, 0.f, 0.f, 0.f};
                #pragma unroll
                for (int f = 0; f < 4; ++f) {
                    U16 ua, ub;
                    ua.u = a[f];
                    ub.u = xf[bt][f];
                    acc = __builtin_amdgcn_mfma_f32_16x16x32_f16(ua.h, ub.h, acc, 0, 0, 0);
                }
                // acc = log2e * 2*x.p_hat  ->  exp2 is a bare v_exp_f32
                sv[bt] += exp2_hw(acc[0]) + exp2_hw(acc[1])
                        + exp2_hw(acc[2]) + exp2_hw(acc[3]);
            }
        }

        #pragma unroll
        for (int bt = 0; bt < 2; ++bt) {
            float v = sv[bt];
            v += __shfl_xor(v, 16, 64);   // combine the 4 row-groups (c's)
            v += __shfl_xor(v, 32, 64);
            if (lane < 16)
                atomicAdd(&nsr[b0 + bg * 32 + bt * 16 + lane], v);
        }
    }
}

// ---------------------------------------------------------------------------
// Finalize: loss = mean_b [ log(w[b]*sum_r negsumR[r][b] - exp(-posd[b]))
//                           + posd[b] ]
// ---------------------------------------------------------------------------
__global__ __launch_bounds__(1024) void final_kernel(
    const float* __restrict__ negsumR, const float* __restrict__ w,
    const float* __restrict__ posd, float* __restrict__ out)
{
    __shared__ float red[1024];
    int t = threadIdx.x;
    float ns = 0.0f;
    #pragma unroll
    for (int r = 0; r < NREP; ++r) ns += negsumR[r * B_N + t];
    float pd = posd[t];
    red[t] = logf(ns * w[t] - __expf(-pd)) + pd;
    __syncthreads();
    #pragma unroll
    for (int s = 512; s > 0; s >>= 1) {
        if (t < s) red[t] += red[t + s];
        __syncthreads();
    }
    if (t == 0) out[0] = red[0] * (1.0f / 1024.0f);
}

extern "C" void kernel_launch(void* const* d_in, const int* in_sizes, int n_in,
                              void* d_out, int out_size, void* d_ws, size_t ws_size,
                              hipStream_t stream)
{
    const float* xs      = (const float*)d_in[0];
    const int*   ys      = (const int*)d_in[1];
    const float* proxies = (const float*)d_in[2];

    char* ws = (char*)d_ws;
    unsigned int* xfrag = (unsigned int*)ws;                 // 256 KB (1024*128 fp16)
    float* w       = (float*)(ws + 262144);                  // 4 KB
    float* posd    = (float*)(ws + 262144 + 4096);           // 4 KB
    float* negsumR = (float*)(ws + 262144 + 8192);           // 32 KB (8 replicas)

    prep_kernel<<<256, 256, 0, stream>>>(xs, ys, proxies, xfrag, w, posd, negsumR);
    main_kernel<<<NBLK_MAIN, 256, 0, stream>>>(proxies, (const uint4*)ws, negsumR);
    final_kernel<<<1, 1024, 0, stream>>>(negsumR, w, posd, (float*)d_out);
}